// Round 7
// baseline (332.981 us; speedup 1.0000x reference)
//
#include <hip/hip_runtime.h>

// entmax-1.5 over rows of an 8192 x 4096 fp32 matrix, boolean mask (int32).
// R7 = R6 (block-per-row, 16 fp32/lane) + two changes:
//  (a) 4 rows per block, software-pipelined: row r+1's 8 loads are issued
//      into registers before row r's solve loop, so HBM stays fed during the
//      solve phase (R6 post-mortem: phase-locked blocks left HBM at 29% while
//      VALU sat at 37% -- nothing saturated, pure serialization).
//  (b) exact piecewise-quadratic solve instead of Newton: on a fixed support,
//      g(tau) = sum(z-tau)^2 - 1 is exactly quadratic; solving it directly
//      (smaller root; vertex jump when disc<0; self-correcting from either
//      side) converges in ~3 sweeps vs Newton's ~6-7, halving barriers.

constexpr int NROWS = 8192;
constexpr int NCOL  = 4096;
constexpr int EPT   = 16;   // elements per thread (4096 / 256)
constexpr int NLD   = 4;    // float4/int4 loads per thread per row
constexpr int RPB   = 4;    // rows per block (pipelined)
constexpr int MAXIT = 8;    // solve cap; typically ~3 sweeps

__global__ __launch_bounds__(256, 6)
void entmax15_kernel(const float* __restrict__ scores,
                     const int*   __restrict__ mask,
                     float*       __restrict__ out)
{
    __shared__ float redA[4], redB[4], redC[4];

    const int tid  = threadIdx.x;
    const int lane = tid & 63;
    const int wave = tid >> 6;

    const size_t row0 = (size_t)blockIdx.x * RPB;
    const float* sp = scores + row0 * NCOL + tid * 4;
    const int*   mp = mask   + row0 * NCOL + tid * 4;
    float*       op = out    + row0 * NCOL + tid * 4;

    // Prefetch registers for the NEXT row (32 VGPRs, live through the solve).
    float4 ps[NLD];
    int4   pm[NLD];
    #pragma unroll
    for (int c = 0; c < NLD; ++c) {
        ps[c] = *reinterpret_cast<const float4*>(sp + c * 1024);
        pm[c] = *reinterpret_cast<const int4*>(mp + c * 1024);
    }

    #pragma unroll 1
    for (int r = 0; r < RPB; ++r) {
        // Consume prefetched row into z (vmcnt waits land here).
        float z[EPT];
        #pragma unroll
        for (int c = 0; c < NLD; ++c) {
            z[c * 4 + 0] = pm[c].x ? ps[c].x * 0.5f : -5000.0f;  // where(mask, s/2, -5000)
            z[c * 4 + 1] = pm[c].y ? ps[c].y * 0.5f : -5000.0f;
            z[c * 4 + 2] = pm[c].z ? ps[c].z * 0.5f : -5000.0f;
            z[c * 4 + 3] = pm[c].w ? ps[c].w * 0.5f : -5000.0f;
        }

        // Issue next row's loads NOW -- they stay in flight through the
        // solve phase (register-destined: no vmcnt drain at barriers).
        sp += NCOL; mp += NCOL;
        if (r + 1 < RPB) {
            #pragma unroll
            for (int c = 0; c < NLD; ++c) {
                ps[c] = *reinterpret_cast<const float4*>(sp + c * 1024);
                pm[c] = *reinterpret_cast<const int4*>(mp + c * 1024);
            }
        }

        // Row max: lane tree, wave butterfly, 4-wave LDS combine.
        float mx = z[0];
        #pragma unroll
        for (int i = 1; i < EPT; ++i) mx = fmaxf(mx, z[i]);
        #pragma unroll
        for (int off = 1; off < 64; off <<= 1)
            mx = fmaxf(mx, __shfl_xor(mx, off, 64));
        __syncthreads();               // redA reuse vs previous row's reads
        if (lane == 0) redA[wave] = mx;
        __syncthreads();
        mx = fmaxf(fmaxf(redA[0], redA[1]), fmaxf(redA[2], redA[3]));

        // Piecewise-exact solve for tau: start at left bracket mx-1.
        // s0 = |support|, s1 = sum d, s2 = sum d^2 (d = relu(z-t)).
        // Solve s0 u^2 - 2 s1 u + (s2-1) = 0; u = (s1 - sqrt(disc))/s0.
        // disc < 0 => no root with this support: jump to vertex (sqrt(0) path).
        // Overshoot self-corrects: from the right s2 < 1 => u < 0.
        float t = mx - 1.0f;
        #pragma unroll 1
        for (int it = 0; it < MAXIT; ++it) {
            float s0 = 0.f, s1 = 0.f, s2 = 0.f;
            #pragma unroll
            for (int i = 0; i < EPT; ++i) {
                const float d = fmaxf(z[i] - t, 0.f);
                s2 = fmaf(d, d, s2);
                s1 += d;
                s0 += (d > 0.f) ? 1.0f : 0.0f;
            }
            #pragma unroll
            for (int off = 1; off < 64; off <<= 1) {
                s0 += __shfl_xor(s0, off, 64);
                s1 += __shfl_xor(s1, off, 64);
                s2 += __shfl_xor(s2, off, 64);
            }
            __syncthreads();           // red* reuse vs previous iteration reads
            if (lane == 0) { redA[wave] = s0; redB[wave] = s1; redC[wave] = s2; }
            __syncthreads();
            s0 = (redA[0] + redA[1]) + (redA[2] + redA[3]);
            s1 = (redB[0] + redB[1]) + (redB[2] + redB[3]);
            s2 = (redC[0] + redC[1]) + (redC[2] + redC[3]);
            const float s0c  = fmaxf(s0, 1.0f);
            const float disc = fmaf(s1, s1, -s0c * (s2 - 1.0f));
            const float u    = (s1 - sqrtf(fmaxf(disc, 0.f))) / s0c;
            t += u;                                    // block-uniform
            if (__builtin_fabsf(u) < 5e-7f) break;     // block-uniform break
        }

        // Epilogue: p = relu(z - tau)^2, coalesced float4 stores.
        #pragma unroll
        for (int c = 0; c < NLD; ++c) {
            float4 o;
            float d;
            d = fmaxf(z[c * 4 + 0] - t, 0.f); o.x = d * d;
            d = fmaxf(z[c * 4 + 1] - t, 0.f); o.y = d * d;
            d = fmaxf(z[c * 4 + 2] - t, 0.f); o.z = d * d;
            d = fmaxf(z[c * 4 + 3] - t, 0.f); o.w = d * d;
            *reinterpret_cast<float4*>(op + c * 1024) = o;
        }
        op += NCOL;
    }
}

extern "C" void kernel_launch(void* const* d_in, const int* in_sizes, int n_in,
                              void* d_out, int out_size, void* d_ws, size_t ws_size,
                              hipStream_t stream)
{
    const float* scores = (const float*)d_in[0];
    const int*   mask   = (const int*)d_in[1];
    float*       out    = (float*)d_out;

    dim3 grid(NROWS / RPB);   // 2048 blocks x 4 pipelined rows
    dim3 block(256);
    hipLaunchKernelGGL(entmax15_kernel, grid, block, 0, stream,
                       scores, mask, out);
}

// Round 8
// 308.864 us; speedup vs baseline: 1.0781x; 1.0781x over previous
//
#include <hip/hip_runtime.h>

// entmax-1.5 over rows of an 8192 x 4096 fp32 matrix, boolean mask (int32).
// R8 = R6 structure (one 256-thread block per row, z[16] fp32 per thread --
// the only layout that ran spill-free) with the solve phase restructured:
//   1) candidates (z > max-1; only these can be in support since tau* >= max-1)
//      are compacted into LDS via ballot+mbcnt, each wave writing its own
//      region (no races, no atomics). ~60 candidates/row on this data.
//   2) every wave redundantly reads all 512 slots (8/lane, sentinel-padded,
//      conflict-free stride-64 layout) and runs the EXACT piecewise-quadratic
//      root iteration with wave-local butterflies only -- ZERO __syncthreads
//      in the solve loop (R6 paid ~14 barriers/row; R8 pays 2).
//   3) overflow rows (>128 cand in one wave's region, >>10 sigma) fall back
//      to R6-style Newton with block-wide reduction.
// State discipline (R5/R7 lesson): keep per-thread live state at z[16]+8 cand
// +temps; no prefetch arrays -- anything past ~40 regs spills to HBM scratch.

constexpr int NROWS = 8192;
constexpr int NCOL  = 4096;
constexpr int EPT   = 16;   // elements per thread (4096 / 256)
constexpr int NLD   = 4;    // float4/int4 loads per thread
constexpr int CAP   = 128;  // candidate slots per wave region
constexpr int MAXIT = 8;    // solve cap; exact-quadratic typically 2-4 iters

static __device__ __forceinline__ int mbcnt64(unsigned long long m) {
    // popcount of m restricted to lanes below this lane
    return __builtin_amdgcn_mbcnt_hi((unsigned)(m >> 32),
           __builtin_amdgcn_mbcnt_lo((unsigned)m, 0));
}

__global__ __launch_bounds__(256, 8)
void entmax15_kernel(const float* __restrict__ scores,
                     const int*   __restrict__ mask,
                     float*       __restrict__ out)
{
    __shared__ float cand[4 * CAP];   // wave w owns [w*CAP, (w+1)*CAP)
    __shared__ float redA[4], redB[4];
    __shared__ int   ovfl;

    const int tid  = threadIdx.x;
    const int lane = tid & 63;
    const int wave = tid >> 6;
    const int row  = blockIdx.x;

    const float* srow = scores + (size_t)row * NCOL;
    const int*   mrow = mask   + (size_t)row * NCOL;
    float*       orow = out    + (size_t)row * NCOL;

    float z[EPT];

    // Coalesced loads: sweep c covers cols [c*1024, c*1024+1024), thread takes
    // 4 consecutive floats at c*1024 + tid*4 (16B aligned).
    #pragma unroll
    for (int c = 0; c < NLD; ++c) {
        const int base = c * 1024 + tid * 4;
        const float4 s4 = *reinterpret_cast<const float4*>(srow + base);
        const int4   m4 = *reinterpret_cast<const int4*>(mrow + base);
        z[c * 4 + 0] = m4.x ? s4.x * 0.5f : -5000.0f;  // where(mask, s/2, -5000)
        z[c * 4 + 1] = m4.y ? s4.y * 0.5f : -5000.0f;
        z[c * 4 + 2] = m4.z ? s4.z * 0.5f : -5000.0f;
        z[c * 4 + 3] = m4.w ? s4.w * 0.5f : -5000.0f;
    }

    // Init (before barrier 1): overflow flag + own region's sentinels.
    // Wave-internal ordering makes the later compaction writes safe.
    if (tid == 0) ovfl = 0;
    cand[wave * CAP + lane]      = -1e30f;
    cand[wave * CAP + lane + 64] = -1e30f;

    // Row max: lane tree, wave butterfly, 4-wave LDS combine (barrier 1).
    float mx = z[0];
    #pragma unroll
    for (int i = 1; i < EPT; ++i) mx = fmaxf(mx, z[i]);
    #pragma unroll
    for (int off = 1; off < 64; off <<= 1)
        mx = fmaxf(mx, __shfl_xor(mx, off, 64));
    if (lane == 0) redA[wave] = mx;
    __syncthreads();
    mx = fmaxf(fmaxf(redA[0], redA[1]), fmaxf(redA[2], redA[3]));
    const float thresh = mx - 1.0f;   // tau* >= thresh: z <= thresh are dead

    // Compact candidates into this wave's region: 16 ballot rounds.
    int cnt = 0;
    #pragma unroll
    for (int i = 0; i < EPT; ++i) {
        const bool isc = z[i] > thresh;
        const unsigned long long m = __ballot(isc);
        if (isc) {
            const int pos = cnt + mbcnt64(m);
            if (pos < CAP) cand[wave * CAP + pos] = z[i];
        }
        cnt += (int)__popcll(m);      // wave-uniform
    }
    if (lane == 0 && cnt > CAP) ovfl = 1;
    __syncthreads();                  // barrier 2: compaction visible

    float t = thresh;                 // left bracket: g(thresh) >= 0

    if (ovfl == 0) {
        // Barrier-free solve: each wave redundantly reads ALL 512 slots,
        // 8 per lane at stride 64 (conflict-free), sentinels give d=0.
        float cv[8];
        #pragma unroll
        for (int k = 0; k < 8; ++k) cv[k] = cand[k * 64 + lane];

        // Exact piecewise-quadratic iteration: on the support at t,
        // s0 u^2 - 2 s1 u + (s2-1) = 0; u = (s1 - sqrt(disc))/s0 (smaller
        // root); disc<0 -> vertex jump; overshoot self-corrects (u<0).
        #pragma unroll 1
        for (int it = 0; it < MAXIT; ++it) {
            float s0 = 0.f, s1 = 0.f, s2 = 0.f;
            #pragma unroll
            for (int k = 0; k < 8; ++k) {
                const float d = fmaxf(cv[k] - t, 0.f);
                s2 = fmaf(d, d, s2);
                s1 += d;
                s0 += (d > 0.f) ? 1.0f : 0.0f;
            }
            #pragma unroll
            for (int off = 1; off < 64; off <<= 1) {
                s0 += __shfl_xor(s0, off, 64);
                s1 += __shfl_xor(s1, off, 64);
                s2 += __shfl_xor(s2, off, 64);
            }
            const float s0c  = fmaxf(s0, 1.0f);     // s0>=1 at t<=tau*<mx
            const float disc = fmaf(s1, s1, -s0c * (s2 - 1.0f));
            const float u    = (s1 - sqrtf(fmaxf(disc, 0.f))) / s0c;
            t += u;                                  // wave-uniform
            if (__builtin_fabsf(u) < 5e-7f) break;   // wave-uniform break
        }
        // All 4 waves computed bit-identical t from identical data.
    } else {
        // Fallback (pathological rows): R6-style Newton, block reduction.
        #pragma unroll 1
        for (int it = 0; it < 10; ++it) {
            float s2 = 0.f, s1 = 0.f;
            #pragma unroll
            for (int i = 0; i < EPT; ++i) {
                const float d = fmaxf(z[i] - t, 0.f);
                s2 = fmaf(d, d, s2);
                s1 += d;
            }
            #pragma unroll
            for (int off = 1; off < 64; off <<= 1) {
                s2 += __shfl_xor(s2, off, 64);
                s1 += __shfl_xor(s1, off, 64);
            }
            __syncthreads();
            if (lane == 0) { redA[wave] = s1; redB[wave] = s2; }
            __syncthreads();
            s1 = (redA[0] + redA[1]) + (redA[2] + redA[3]);
            s2 = (redB[0] + redB[1]) + (redB[2] + redB[3]);
            const float step = (s2 - 1.0f) / (2.0f * s1);
            t += step;                                  // block-uniform
            if (__builtin_fabsf(step) < 5e-7f) break;   // block-uniform
        }
    }

    // Epilogue: p = relu(z - tau)^2, coalesced float4 stores.
    #pragma unroll
    for (int c = 0; c < NLD; ++c) {
        const int base = c * 1024 + tid * 4;
        float4 o;
        float d;
        d = fmaxf(z[c * 4 + 0] - t, 0.f); o.x = d * d;
        d = fmaxf(z[c * 4 + 1] - t, 0.f); o.y = d * d;
        d = fmaxf(z[c * 4 + 2] - t, 0.f); o.z = d * d;
        d = fmaxf(z[c * 4 + 3] - t, 0.f); o.w = d * d;
        *reinterpret_cast<float4*>(orow + base) = o;
    }
}

extern "C" void kernel_launch(void* const* d_in, const int* in_sizes, int n_in,
                              void* d_out, int out_size, void* d_ws, size_t ws_size,
                              hipStream_t stream)
{
    const float* scores = (const float*)d_in[0];
    const int*   mask   = (const int*)d_in[1];
    float*       out    = (float*)d_out;

    dim3 grid(NROWS);    // one 256-thread block per row
    dim3 block(256);
    hipLaunchKernelGGL(entmax15_kernel, grid, block, 0, stream,
                       scores, mask, out);
}